// Round 2
// baseline (1771.022 us; speedup 1.0000x reference)
//
#include <hip/hip_runtime.h>
#include <stdint.h>

// Problem constants (from reference setup_inputs)
#define B_  64
#define LA  512
#define LB  512
#define DD  768
#define NEGV -100000.0f
#define NB  512            // grid size; 2 blocks/CU resident (launch_bounds(256,2))

typedef __attribute__((ext_vector_type(8))) short bf16x8;
typedef __attribute__((ext_vector_type(4))) float f32x4;

__device__ __forceinline__ unsigned short f2bf(float x) {
    union { float f; unsigned u; } v; v.f = x;
    unsigned r = v.u + 0x7fffu + ((v.u >> 16) & 1u);   // RNE
    return (unsigned short)(r >> 16);
}
__device__ __forceinline__ float bf2f(unsigned short h) {
    union { float f; unsigned u; } v; v.u = ((unsigned)h) << 16;
    return v.f;
}

// global_load_lds: LDS dest is wave-uniform base + lane*16 (linear); global src per-lane.
#define GLD16(gp, lp) __builtin_amdgcn_global_load_lds( \
    (const __attribute__((address_space(1))) void*)(gp), \
    (__attribute__((address_space(3))) void*)(lp), 16, 0, 0)

// ---------------------------------------------------------------------------
// Grid-wide barrier: generation counter, agent-scope (cross-XCD safe).
// All NB blocks are resident (2/CU x 256 CU), so spinning is deadlock-free.
// ---------------------------------------------------------------------------
__device__ __forceinline__ void gridbar(unsigned* cnt, unsigned* gen) {
    __syncthreads();                       // all waves' stores drained (vmcnt0 before s_barrier)
    if (threadIdx.x == 0) {
        __threadfence();                   // agent-scope release: L2 writeback
        unsigned g0 = __hip_atomic_load(gen, __ATOMIC_ACQUIRE, __HIP_MEMORY_SCOPE_AGENT);
        unsigned t = __hip_atomic_fetch_add(cnt, 1u, __ATOMIC_ACQ_REL, __HIP_MEMORY_SCOPE_AGENT);
        if (t == NB - 1) {
            __hip_atomic_store(cnt, 0u, __ATOMIC_RELAXED, __HIP_MEMORY_SCOPE_AGENT);
            __hip_atomic_fetch_add(gen, 1u, __ATOMIC_ACQ_REL, __HIP_MEMORY_SCOPE_AGENT);
        } else {
            while (__hip_atomic_load(gen, __ATOMIC_ACQUIRE, __HIP_MEMORY_SCOPE_AGENT) == g0)
                __builtin_amdgcn_s_sleep(8);
        }
        __threadfence();                   // agent-scope acquire: L1/L2 invalidate
    }
    __syncthreads();
}

__global__ void init_sync_k(unsigned* cnt, unsigned* gen) {
    if (threadIdx.x == 0) { *cnt = 0u; *gen = 0u; }
}

// ---------------------------------------------------------------------------
// Megakernel: P1 prep -> P2 egemm -> P3 stats -> P4 pgen -> P5 pv(a)+pv(b)
// All phase job counts are exact multiples of NB (uniform barrier arrival).
// ---------------------------------------------------------------------------
__global__ __launch_bounds__(256, 2)
void mega_k(const float* __restrict__ a, const float* __restrict__ b,
            const int* __restrict__ mask_a, const int* __restrict__ mask_b,
            float* __restrict__ e,
            unsigned short* __restrict__ aT, unsigned short* __restrict__ bT,
            unsigned short* __restrict__ ahi, unsigned short* __restrict__ alo,
            unsigned short* __restrict__ bhi, unsigned short* __restrict__ blo,
            float* __restrict__ rmax, float* __restrict__ rinv,
            float* __restrict__ cmax, float* __restrict__ cinv,
            unsigned short* __restrict__ Pa, unsigned short* __restrict__ PbT,
            float* __restrict__ out_a, float* __restrict__ out_b,
            unsigned* cnt, unsigned* gen)
{
    __shared__ __align__(16) unsigned char SMEM[32768];
    const int bid = blockIdx.x;
    const int tid = threadIdx.x;

    // =======================================================================
    // P1: prep both inputs. x fp32 -> xT bf16 (swizzled), xh/xl bf16 hi/lo
    // (swizzled). 12288 tile jobs (2 sides x 8 x 12 x 64), 24 per block.
    // =======================================================================
    {
        unsigned short (*tile)[65] = reinterpret_cast<unsigned short(*)[65]>(SMEM);
        const int c4 = (tid & 15) * 4;
        const int r0 = tid >> 4;
        const int c = tid & 63, rr = tid >> 6;
        for (int job = bid; job < 12288; job += NB) {
            __syncthreads();               // protect tile reuse across jobs
            const int side = (job >= 6144);
            const int j = side ? job - 6144 : job;
            const int x = j & 7, y = (j >> 3) % 12, bb = j / 96;
            const int l0 = x * 64, d0 = y * 64;
            const float* xp = (side ? b : a) + (size_t)bb * 512 * DD;
            unsigned short* tp = (side ? bT : aT) + (size_t)bb * DD * 512;
            unsigned short* hp = (side ? bhi : ahi) + (size_t)bb * 512 * DD;
            unsigned short* lp = (side ? blo : alo) + (size_t)bb * 512 * DD;
#pragma unroll
            for (int s = 0; s < 4; ++s) {
                const int r = r0 + s * 16;
                const int l = l0 + r;
                float4 v = *(const float4*)(xp + (size_t)l * DD + d0 + c4);
                ushort4 h, lo;
                h.x = f2bf(v.x); lo.x = f2bf(v.x - bf2f(h.x));
                h.y = f2bf(v.y); lo.y = f2bf(v.y - bf2f(h.y));
                h.z = f2bf(v.z); lo.z = f2bf(v.z - bf2f(h.z));
                h.w = f2bf(v.w); lo.w = f2bf(v.w - bf2f(h.w));
                tile[r][c4 + 0] = h.x; tile[r][c4 + 1] = h.y;
                tile[r][c4 + 2] = h.z; tile[r][c4 + 3] = h.w;
                const int qp = (((c4 >> 3) ^ (r >> 1)) & 3) << 3;
                const int dp = d0 + (c4 & ~31) + qp + (c4 & 7);
                *(ushort4*)&hp[(size_t)l * DD + dp] = h;
                *(ushort4*)&lp[(size_t)l * DD + dp] = lo;
            }
            __syncthreads();
#pragma unroll
            for (int s = 0; s < 16; ++s) {
                const int r = rr + s * 4;                       // row of xT = d-index
                const int qp = (((c >> 3) ^ (r >> 1)) & 3) << 3;
                const int cp = l0 + (c & ~31) + qp + (c & 7);   // swizzled l-index
                tp[(size_t)(d0 + r) * 512 + cp] = tile[c][r];
            }
        }
    }
    gridbar(cnt, gen);

    // =======================================================================
    // P2: egemm (bf16x3 split, fp32-accurate). 1024 tile jobs, 2 per block.
    // Pure global_load_lds staging; swizzled ds_read_b128 fragments.
    // =======================================================================
    {
        unsigned short* Ah = (unsigned short*)SMEM;
        unsigned short* Al = Ah + 4096;
        unsigned short* Bh = Ah + 8192;
        unsigned short* Bl = Ah + 12288;
        const int lane = tid & 63, w = tid >> 6;
        const int wm = (w >> 1) * 64, wn = (w & 1) * 64;
        const int lrow = lane & 15, qsel = lane >> 4;
        const int poff = ((qsel ^ (lrow >> 1)) & 3) << 3;
        const int sr0 = (2 * w) * 16 + (lane >> 2);
        const int sc = (lane & 3) * 8;
        unsigned short* la0 = &Ah[(2 * w) * 512]; unsigned short* la1 = la0 + 512;
        unsigned short* ll0 = &Al[(2 * w) * 512]; unsigned short* ll1 = ll0 + 512;
        unsigned short* lb0 = &Bh[(2 * w) * 512]; unsigned short* lb1 = lb0 + 512;
        unsigned short* lm0 = &Bl[(2 * w) * 512]; unsigned short* lm1 = lm0 + 512;

        for (int job = bid; job < 1024; job += NB) {
            const int bb = job >> 4, t = job & 15;
            const int m0 = (t & 3) * 128, n0 = (t >> 2) * 128;
            const size_t boff = (size_t)bb * 512 * DD;
            const unsigned short* pa0 = ahi + boff + (size_t)(m0 + sr0) * DD + sc;
            const unsigned short* pa1 = pa0 + 16 * DD;
            const unsigned short* pl0 = alo + boff + (size_t)(m0 + sr0) * DD + sc;
            const unsigned short* pl1 = pl0 + 16 * DD;
            const unsigned short* pb0 = bhi + boff + (size_t)(n0 + sr0) * DD + sc;
            const unsigned short* pb1 = pb0 + 16 * DD;
            const unsigned short* pm0 = blo + boff + (size_t)(n0 + sr0) * DD + sc;
            const unsigned short* pm1 = pm0 + 16 * DD;

            f32x4 acc[4][4] = {};
            for (int k0 = 0; k0 < DD; k0 += 32) {
                GLD16(pa0 + k0, la0); GLD16(pa1 + k0, la1);
                GLD16(pl0 + k0, ll0); GLD16(pl1 + k0, ll1);
                GLD16(pb0 + k0, lb0); GLD16(pb1 + k0, lb1);
                GLD16(pm0 + k0, lm0); GLD16(pm1 + k0, lm1);
                __syncthreads();           // vmcnt(0) drain + barrier
                bf16x8 ahf[4], alf[4], bhf[4], blf[4];
#pragma unroll
                for (int mi = 0; mi < 4; ++mi) {
                    const int R = wm + mi * 16 + lrow;
                    ahf[mi] = *(const bf16x8*)&Ah[R * 32 + poff];
                    alf[mi] = *(const bf16x8*)&Al[R * 32 + poff];
                }
#pragma unroll
                for (int ni = 0; ni < 4; ++ni) {
                    const int R = wn + ni * 16 + lrow;
                    bhf[ni] = *(const bf16x8*)&Bh[R * 32 + poff];
                    blf[ni] = *(const bf16x8*)&Bl[R * 32 + poff];
                }
#pragma unroll
                for (int mi = 0; mi < 4; ++mi)
#pragma unroll
                    for (int ni = 0; ni < 4; ++ni) {
                        acc[mi][ni] = __builtin_amdgcn_mfma_f32_16x16x32_bf16(alf[mi], bhf[ni], acc[mi][ni], 0, 0, 0);
                        acc[mi][ni] = __builtin_amdgcn_mfma_f32_16x16x32_bf16(ahf[mi], blf[ni], acc[mi][ni], 0, 0, 0);
                        acc[mi][ni] = __builtin_amdgcn_mfma_f32_16x16x32_bf16(ahf[mi], bhf[ni], acc[mi][ni], 0, 0, 0);
                    }
                __syncthreads();
            }

            const int* map = mask_a + bb * LA;
            const int* mbp = mask_b + bb * LB;
            float* ep = e + (size_t)bb * LA * LB;
            const int colbase = n0 + wn + (lane & 15);
            const int rowbase = m0 + wm + (lane >> 4) * 4;
#pragma unroll
            for (int mi = 0; mi < 4; ++mi)
#pragma unroll
                for (int ni = 0; ni < 4; ++ni) {
                    const int jx = colbase + ni * 16;
                    const float mbf = (float)mbp[jx];
#pragma unroll
                    for (int r = 0; r < 4; ++r) {
                        const int ix = rowbase + mi * 16 + r;
                        const float mm = (float)map[ix] * mbf;
                        // plain store: e stays L2/L3-resident for the 3 readers
                        ep[(size_t)ix * LB + jx] = (mm < 0.5f) ? NEGV : acc[mi][ni][r];
                    }
                }
        }
    }
    gridbar(cnt, gen);

    // =======================================================================
    // P3: softmax stats. colstats: 512 jobs (1/block). rowstats: 8192 quad
    // jobs (16/block). e is L3-hot from P2.
    // =======================================================================
    {
        // ---- colstats (axis=1): online max/sum down 128-row segments ----
        float* sm = (float*)SMEM;            // [4][64]
        float* ss = sm + 256;
        const int jj = tid & 63, seg = tid >> 6;
        const int j0 = (bid & 7) * 64, bb = bid >> 3;
        const float* ep = e + (size_t)bb * LA * LB + (size_t)seg * 128 * LB + j0 + jj;
        float m = -3.4e38f, s = 0.f;
        for (int i = 0; i < 128; ++i) {
            const float v = ep[(size_t)i * LB];
            const float nm = fmaxf(m, v);
            s = s * __expf(m - nm) + __expf(v - nm);
            m = nm;
        }
        sm[seg * 64 + jj] = m; ss[seg * 64 + jj] = s;
        __syncthreads();
        if (seg == 0) {
            const float m0 = sm[jj], m1 = sm[64 + jj], m2 = sm[128 + jj], m3 = sm[192 + jj];
            const float M = fmaxf(fmaxf(m0, m1), fmaxf(m2, m3));
            const float S = ss[jj] * __expf(m0 - M) + ss[64 + jj] * __expf(m1 - M)
                          + ss[128 + jj] * __expf(m2 - M) + ss[192 + jj] * __expf(m3 - M);
            cmax[bb * LB + j0 + jj] = M;
            cinv[bb * LB + j0 + jj] = 1.0f / S;
        }
        // ---- rowstats (axis=2): one wave per row, 16 quad-jobs/block ----
        const int lane = tid & 63;
        for (int q = 0; q < 16; ++q) {
            const int row = (bid + q * NB) * 4 + (tid >> 6);
            const float* rp = e + (size_t)row * LB;
            float4 v1 = *(const float4*)(rp + lane * 8);
            float4 v2 = *(const float4*)(rp + lane * 8 + 4);
            float rm = fmaxf(fmaxf(fmaxf(v1.x, v1.y), fmaxf(v1.z, v1.w)),
                             fmaxf(fmaxf(v2.x, v2.y), fmaxf(v2.z, v2.w)));
#pragma unroll
            for (int o = 32; o; o >>= 1) rm = fmaxf(rm, __shfl_xor(rm, o));
            float rs = __expf(v1.x - rm) + __expf(v1.y - rm) + __expf(v1.z - rm) + __expf(v1.w - rm)
                     + __expf(v2.x - rm) + __expf(v2.y - rm) + __expf(v2.z - rm) + __expf(v2.w - rm);
#pragma unroll
            for (int o = 32; o; o >>= 1) rs += __shfl_xor(rs, o);
            if (lane == 0) { rmax[row] = rm; rinv[row] = 1.0f / rs; }
        }
    }
    gridbar(cnt, gen);

    // =======================================================================
    // P4: pgen. Pa (softmax axis2) + PbT (softmax axis1, transposed), bf16,
    // swizzled layout for P5's global_load_lds. 4096 jobs, 8 per block.
    // =======================================================================
    {
        unsigned short (*tile)[65] = reinterpret_cast<unsigned short(*)[65]>(SMEM);
        const int c = tid & 63, r0 = tid >> 6;
        for (int job = bid; job < 4096; job += NB) {
            __syncthreads();               // protect tile reuse across jobs
            const int i0 = (job & 7) * 64, j0 = ((job >> 3) & 7) * 64, bb = job >> 6;
            const float* ep = e + (size_t)bb * LA * LB;
            const float cm = cmax[bb * LB + j0 + c];
            const float ci = cinv[bb * LB + j0 + c];
#pragma unroll
            for (int s = 0; s < 16; ++s) {
                const int r = r0 + s * 4;
                const float rm = rmax[bb * LA + i0 + r];
                const float ri = rinv[bb * LA + i0 + r];
                const float v = ep[(size_t)(i0 + r) * LB + j0 + c];
                const int qp = (((c >> 3) ^ (r >> 1)) & 3) << 3;
                const int jp = j0 + (c & ~31) + qp + (c & 7);
                Pa[((size_t)bb * LA + i0 + r) * LB + jp] = f2bf(__expf(v - rm) * ri);
                tile[r][c] = f2bf(__expf(v - cm) * ci);
            }
            __syncthreads();
#pragma unroll
            for (int s = 0; s < 16; ++s) {
                const int r = r0 + s * 4;                       // row of PbT = j-index
                const int qp = (((c >> 3) ^ (r >> 1)) & 3) << 3;
                const int ip = i0 + (c & ~31) + qp + (c & 7);   // swizzled i-index
                PbT[((size_t)bb * LB + j0 + r) * LA + ip] = tile[c][r];
            }
        }
    }
    gridbar(cnt, gen);

    // =======================================================================
    // P5: pv for both sides with fused concat epilogue. 3072 jobs, 6/block.
    // =======================================================================
    {
        unsigned short* At = (unsigned short*)SMEM;
        unsigned short* Bt = At + 4096;
        const int lane = tid & 63, w = tid >> 6;
        const int wm = (w >> 1) * 64, wn = (w & 1) * 64;
        const int lrow = lane & 15, qsel = lane >> 4;
        const int poff = ((qsel ^ (lrow >> 1)) & 3) << 3;
        const int sr0 = (2 * w) * 16 + (lane >> 2);
        const int sc = (lane & 3) * 8;
        unsigned short* lA0 = &At[(2 * w) * 512]; unsigned short* lA1 = lA0 + 512;
        unsigned short* lB0 = &Bt[(2 * w) * 512]; unsigned short* lB1 = lB0 + 512;

        for (int job = bid; job < 3072; job += NB) {
            const int side = (job >= 1536);
            const int jj = side ? job - 1536 : job;
            const int bb = jj / 24;
            const int t = jj - bb * 24;
            const int m0 = (t & 3) * 128, n0 = (t >> 2) * 128;   // 4 x 6 tiles
            const unsigned short* Pp = (side ? PbT : Pa) + (size_t)bb * 512 * 512;
            const unsigned short* Vp = (side ? aT : bT) + (size_t)bb * DD * 512;
            const float* Xp = (side ? b : a) + (size_t)bb * 512 * DD;
            float* op = (side ? out_b : out_a) + (size_t)bb * 512 * (4 * DD);

            const unsigned short* p0 = Pp + (size_t)(m0 + sr0) * 512 + sc;
            const unsigned short* p1 = p0 + 16 * 512;
            const unsigned short* v0 = Vp + (size_t)(n0 + sr0) * 512 + sc;
            const unsigned short* v1 = v0 + 16 * 512;

            f32x4 acc[4][4] = {};
            for (int k0 = 0; k0 < 512; k0 += 32) {
                GLD16(p0 + k0, lA0); GLD16(p1 + k0, lA1);
                GLD16(v0 + k0, lB0); GLD16(v1 + k0, lB1);
                __syncthreads();
                bf16x8 af[4], bf_[4];
#pragma unroll
                for (int mi = 0; mi < 4; ++mi)
                    af[mi] = *(const bf16x8*)&At[(wm + mi * 16 + lrow) * 32 + poff];
#pragma unroll
                for (int ni = 0; ni < 4; ++ni)
                    bf_[ni] = *(const bf16x8*)&Bt[(wn + ni * 16 + lrow) * 32 + poff];
#pragma unroll
                for (int mi = 0; mi < 4; ++mi)
#pragma unroll
                    for (int ni = 0; ni < 4; ++ni)
                        acc[mi][ni] = __builtin_amdgcn_mfma_f32_16x16x32_bf16(af[mi], bf_[ni], acc[mi][ni], 0, 0, 0);
                __syncthreads();
            }

            const int colbase = n0 + wn + (lane & 15);
            const int rowbase = m0 + wm + (lane >> 4) * 4;
#pragma unroll
            for (int mi = 0; mi < 4; ++mi)
#pragma unroll
                for (int ni = 0; ni < 4; ++ni) {
                    const int d = colbase + ni * 16;
#pragma unroll
                    for (int r = 0; r < 4; ++r) {
                        const int ix = rowbase + mi * 16 + r;
                        const float tv = acc[mi][ni][r];
                        const float xv = Xp[(size_t)ix * DD + d];
                        float* o = op + (size_t)ix * (4 * DD) + d;
                        __builtin_nontemporal_store(xv, o);
                        __builtin_nontemporal_store(tv, o + DD);
                        __builtin_nontemporal_store(xv - tv, o + 2 * DD);
                        __builtin_nontemporal_store(xv * tv, o + 3 * DD);
                    }
                }
        }
    }
}

// ---------------------------------------------------------------------------
extern "C" void kernel_launch(void* const* d_in, const int* in_sizes, int n_in,
                              void* d_out, int out_size, void* d_ws, size_t ws_size,
                              hipStream_t stream) {
    const float* a      = (const float*)d_in[0];
    const int*   mask_a = (const int*)d_in[1];
    const float* b      = (const float*)d_in[2];
    const int*   mask_b = (const int*)d_in[3];
    float* out = (float*)d_out;

    uint8_t* w = (uint8_t*)d_ws;
    float* e            = (float*)w;          w += (size_t)B_ * LA * LB * 4;   // 67.1 MB
    unsigned short* aT  = (unsigned short*)w; w += (size_t)B_ * DD * LA * 2;   // 50.3 MB
    unsigned short* bT  = (unsigned short*)w; w += (size_t)B_ * DD * LB * 2;   // 50.3 MB
    unsigned short* ahi = (unsigned short*)w; w += (size_t)B_ * LA * DD * 2;   // 50.3 MB
    unsigned short* alo = (unsigned short*)w; w += (size_t)B_ * LA * DD * 2;   // 50.3 MB
    unsigned short* bhi = (unsigned short*)w; w += (size_t)B_ * LB * DD * 2;   // 50.3 MB
    unsigned short* blo = (unsigned short*)w; w += (size_t)B_ * LB * DD * 2;   // 50.3 MB
    unsigned short* Pa  = (unsigned short*)w; w += (size_t)B_ * LA * LB * 2;   // 33.6 MB
    unsigned short* PbT = (unsigned short*)w; w += (size_t)B_ * LB * LA * 2;   // 33.6 MB
    float* rmax = (float*)w; w += (size_t)B_ * LA * 4;
    float* rinv = (float*)w; w += (size_t)B_ * LA * 4;
    float* cmax = (float*)w; w += (size_t)B_ * LB * 4;
    float* cinv = (float*)w; w += (size_t)B_ * LB * 4;
    unsigned* cnt = (unsigned*)w; w += 64;
    unsigned* gen = (unsigned*)w; w += 64;
    // total ~437 MB

    float* out_a = out;
    float* out_b = out + (size_t)B_ * LA * (4 * DD);

    init_sync_k<<<1, 64, 0, stream>>>(cnt, gen);
    mega_k<<<NB, 256, 0, stream>>>(a, b, mask_a, mask_b, e,
                                   aT, bT, ahi, alo, bhi, blo,
                                   rmax, rinv, cmax, cinv, Pa, PbT,
                                   out_a, out_b, cnt, gen);
}